// Round 2
// baseline (178.152 us; speedup 1.0000x reference)
//
#include <hip/hip_runtime.h>
#include <cstdint>
#include <cstddef>

// All tensors are FP32 per the reference dtypes.
// Shapes: b=2, n=512, m=256, d=32, t=128, ORDER=2, C_OUT=64
// fc:  [b,n,d,t]   ft: [b,m,d,t]   adj: [b,2,m,n]   mask: [b,t,n]
// W: [64,96]  bias: [64]  out y: [b,m,64,t]
//
// Algebra: norm = a / (sum_n a + 1) with a = adj * (1-mask); the denominator is
// constant over n, so:
//   s[bi,m,t]   = sum_n adj[bi,m,n] * w[b,n,t]          (w = 1-mask, transposed)
//   u[bi,m,d,t] = sum_n adj[bi,m,n] * fc[b,n,d,t]*w[b,n,t]
//   agg_i       = ft + u_i / (s_i + 1)
//   y = relu(bias + W @ concat(ft, agg0, agg1))

// ---------- kernel 0: wT[b,n,t] = 1 - mask[b,t,n] (LDS tile transpose) ----------
__global__ void k_wt(const float* __restrict__ mask, float* __restrict__ wT) {
    const int nt = blockIdx.x;   // 16 tiles of 32 n
    const int tt = blockIdx.y;   // 4 tiles of 32 t
    const int b  = blockIdx.z;   // 2
    const int tid = threadIdx.x; // 256
    __shared__ float lds[32][33];
    const int n0 = nt * 32, t0 = tt * 32;
    #pragma unroll
    for (int j = 0; j < 4; ++j) {
        int l = j * 256 + tid;          // 0..1023
        int trow = l >> 5, ncol = l & 31;
        lds[ncol][trow] = mask[((size_t)b << 16) + (size_t)(t0 + trow) * 512 + (n0 + ncol)];
    }
    __syncthreads();
    #pragma unroll
    for (int j = 0; j < 4; ++j) {
        int l = j * 256 + tid;
        int nrow = l >> 5, tcol = l & 31;
        wT[((size_t)b << 16) + (size_t)(n0 + nrow) * 128 + (t0 + tcol)] = 1.0f - lds[nrow][tcol];
    }
}

// ---------- kernel A: s[bi,m,t] = sum_n adj[bi,m,n] * wT[b,n,t] ----------
__global__ void k_s(const float* __restrict__ adj, const float* __restrict__ wT,
                    float* __restrict__ s) {
    const int m = blockIdx.x;     // 256
    const int bi = blockIdx.y;    // 4 = b*2+i
    const int b = bi >> 1;
    const int t = threadIdx.x;    // 128
    __shared__ float arow[512];
    const float* ap = adj + ((size_t)bi * 256 + m) * 512;
    for (int i = threadIdx.x; i < 512; i += 128) arow[i] = ap[i];
    __syncthreads();
    const float* wp = wT + ((size_t)b << 16) + t;
    float a0 = 0.f, a1 = 0.f, a2 = 0.f, a3 = 0.f;
    for (int n = 0; n < 512; n += 4) {
        a0 += arow[n]     * wp[(size_t)n * 128];
        a1 += arow[n + 1] * wp[(size_t)(n + 1) * 128];
        a2 += arow[n + 2] * wp[(size_t)(n + 2) * 128];
        a3 += arow[n + 3] * wp[(size_t)(n + 3) * 128];
    }
    s[((size_t)bi * 256 + m) * 128 + t] = (a0 + a1) + (a2 + a3);
}

// ---------- kernel B: u[bi,m,d,t] = sum_n adj[bi,m,n] * fc[b,n,d,t]*wT[b,n,t] ----------
// grid: x = m-tile (8 tiles of 32), y = d (32), z = bi (4). 256 threads.
// thread: mq = tid>>5 (4 m's), tq = tid&31 (4 t's) -> 4x4 float acc.
__launch_bounds__(256)
__global__ void k_u(const float* __restrict__ fc, const float* __restrict__ adj,
                    const float* __restrict__ wT, float* __restrict__ u) {
    const int mt  = blockIdx.x;
    const int d   = blockIdx.y;
    const int bi  = blockIdx.z;
    const int b   = bi >> 1;
    const int tid = threadIdx.x;
    __shared__ float4 gv4[8][32];   // [nk][t/4]
    __shared__ float4 av4[8][8];    // [nk][m/4]
    float* avs = (float*)av4;
    const int tq = tid & 31;
    const int mq = tid >> 5;
    float4 acc0 = make_float4(0.f,0.f,0.f,0.f);
    float4 acc1 = make_float4(0.f,0.f,0.f,0.f);
    float4 acc2 = make_float4(0.f,0.f,0.f,0.f);
    float4 acc3 = make_float4(0.f,0.f,0.f,0.f);

    const int lidx = tid << 2;       // 0..1020
    const int lnk  = lidx >> 7;      // 0..7
    const int ltb  = lidx & 127;     // 0..124 (step 4)
    const int amm  = tid >> 3;       // 0..31
    const int ank  = tid & 7;        // 0..7
    const float* fbase = fc + (size_t)b * 2097152 + (size_t)d * 128 + ltb;
    const float* wbase = wT + ((size_t)b << 16) + ltb;
    const float* abase = adj + ((size_t)bi * 256 + mt * 32 + amm) * 512 + ank;

    for (int n0 = 0; n0 < 512; n0 += 8) {
        __syncthreads();
        {
            int n = n0 + lnk;
            float4 f4 = *(const float4*)(fbase + (size_t)n * 4096);
            float4 w4 = *(const float4*)(wbase + (size_t)n * 128);
            float4 g;
            g.x = f4.x * w4.x;
            g.y = f4.y * w4.y;
            g.z = f4.z * w4.z;
            g.w = f4.w * w4.w;
            gv4[lnk][ltb >> 2] = g;
            avs[ank * 32 + amm] = abase[n0];
        }
        __syncthreads();
        #pragma unroll
        for (int nk = 0; nk < 8; ++nk) {
            float4 g = gv4[nk][tq];
            float4 a = av4[nk][mq];
            acc0.x += a.x * g.x; acc0.y += a.x * g.y; acc0.z += a.x * g.z; acc0.w += a.x * g.w;
            acc1.x += a.y * g.x; acc1.y += a.y * g.y; acc1.z += a.y * g.z; acc1.w += a.y * g.w;
            acc2.x += a.z * g.x; acc2.y += a.z * g.y; acc2.z += a.z * g.z; acc2.w += a.z * g.w;
            acc3.x += a.w * g.x; acc3.y += a.w * g.y; acc3.z += a.w * g.z; acc3.w += a.w * g.w;
        }
    }
    const size_t mbase = (size_t)bi * 256 + mt * 32 + mq * 4;
    float4* u0 = (float4*)(u + ((mbase + 0) * 32 + d) * 128 + tq * 4);
    float4* u1 = (float4*)(u + ((mbase + 1) * 32 + d) * 128 + tq * 4);
    float4* u2 = (float4*)(u + ((mbase + 2) * 32 + d) * 128 + tq * 4);
    float4* u3 = (float4*)(u + ((mbase + 3) * 32 + d) * 128 + tq * 4);
    *u0 = acc0; *u1 = acc1; *u2 = acc2; *u3 = acc3;
}

// ---------- kernel C: y[b,m,o,t] = relu(bias + W@[ft; ft+u0*r0; ft+u1*r1]) ----------
// grid: x = m (256), y = b (2). 256 threads: og = tid>>4 (4 o's), tg = tid&15 (8 t's).
__launch_bounds__(256)
__global__ void k_mlp(const float* __restrict__ ft, const float* __restrict__ u,
                      const float* __restrict__ s, const float* __restrict__ W,
                      const float* __restrict__ bias, float* __restrict__ y) {
    const int m = blockIdx.x;
    const int b = blockIdx.y;
    const int tid = threadIdx.x;
    const int og = tid >> 4;     // 0..15 -> o = og*4..+3
    const int tg = tid & 15;     // t = tg*8..+7
    __shared__ float Wl[64 * 97];
    __shared__ float bl[64];
    for (int idx = tid; idx < 6144; idx += 256) {
        int o = idx / 96, c = idx - o * 96;
        Wl[o * 97 + c] = W[idx];
    }
    if (tid < 64) bl[tid] = bias[tid];
    __syncthreads();

    const int t0 = tg * 8;
    float r0[8], r1[8];
    {
        const float* s0 = s + (((size_t)b * 2 + 0) * 256 + m) * 128 + t0;
        const float* s1 = s + (((size_t)b * 2 + 1) * 256 + m) * 128 + t0;
        #pragma unroll
        for (int k = 0; k < 8; ++k) {
            r0[k] = 1.0f / (s0[k] + 1.0f);
            r1[k] = 1.0f / (s1[k] + 1.0f);
        }
    }
    float acc[4][8];
    #pragma unroll
    for (int oj = 0; oj < 4; ++oj) {
        float bv = bl[og * 4 + oj];
        #pragma unroll
        for (int k = 0; k < 8; ++k) acc[oj][k] = bv;
    }
    const float* fp  = ft + ((size_t)b * 256 + m) * 4096 + t0;
    const float* u0p = u + (((size_t)b * 2 + 0) * 256 + m) * 4096 + t0;
    const float* u1p = u + (((size_t)b * 2 + 1) * 256 + m) * 4096 + t0;

    for (int d = 0; d < 32; ++d) {
        float4 fa = *(const float4*)(fp + (size_t)d * 128);
        float4 fb = *(const float4*)(fp + (size_t)d * 128 + 4);
        float ftv[8] = { fa.x, fa.y, fa.z, fa.w, fb.x, fb.y, fb.z, fb.w };
        float4 ua = *(const float4*)(u0p + (size_t)d * 128);
        float4 ub = *(const float4*)(u0p + (size_t)d * 128 + 4);
        float4 va = *(const float4*)(u1p + (size_t)d * 128);
        float4 vb = *(const float4*)(u1p + (size_t)d * 128 + 4);
        float a0[8] = { ftv[0] + ua.x * r0[0], ftv[1] + ua.y * r0[1],
                        ftv[2] + ua.z * r0[2], ftv[3] + ua.w * r0[3],
                        ftv[4] + ub.x * r0[4], ftv[5] + ub.y * r0[5],
                        ftv[6] + ub.z * r0[6], ftv[7] + ub.w * r0[7] };
        float a1[8] = { ftv[0] + va.x * r1[0], ftv[1] + va.y * r1[1],
                        ftv[2] + va.z * r1[2], ftv[3] + va.w * r1[3],
                        ftv[4] + vb.x * r1[4], ftv[5] + vb.y * r1[5],
                        ftv[6] + vb.z * r1[6], ftv[7] + vb.w * r1[7] };
        #pragma unroll
        for (int oj = 0; oj < 4; ++oj) {
            int o = og * 4 + oj;
            float w0 = Wl[o * 97 + d];
            float w1 = Wl[o * 97 + 32 + d];
            float w2 = Wl[o * 97 + 64 + d];
            #pragma unroll
            for (int k = 0; k < 8; ++k)
                acc[oj][k] += w0 * ftv[k] + w1 * a0[k] + w2 * a1[k];
        }
    }
    float* yp = y + (((size_t)b * 256 + m) * 64 + og * 4) * 128 + t0;
    #pragma unroll
    for (int oj = 0; oj < 4; ++oj) {
        float4 pa, pb;
        pa.x = acc[oj][0] > 0.f ? acc[oj][0] : 0.f;
        pa.y = acc[oj][1] > 0.f ? acc[oj][1] : 0.f;
        pa.z = acc[oj][2] > 0.f ? acc[oj][2] : 0.f;
        pa.w = acc[oj][3] > 0.f ? acc[oj][3] : 0.f;
        pb.x = acc[oj][4] > 0.f ? acc[oj][4] : 0.f;
        pb.y = acc[oj][5] > 0.f ? acc[oj][5] : 0.f;
        pb.z = acc[oj][6] > 0.f ? acc[oj][6] : 0.f;
        pb.w = acc[oj][7] > 0.f ? acc[oj][7] : 0.f;
        *(float4*)(yp + (size_t)oj * 128)     = pa;
        *(float4*)(yp + (size_t)oj * 128 + 4) = pb;
    }
}

extern "C" void kernel_launch(void* const* d_in, const int* in_sizes, int n_in,
                              void* d_out, int out_size, void* d_ws, size_t ws_size,
                              hipStream_t stream) {
    const float* fc   = (const float*)d_in[0]; // [2,512,32,128]
    const float* ft   = (const float*)d_in[1]; // [2,256,32,128]
    const float* adj  = (const float*)d_in[2]; // [2,2,256,512]
    const float* mask = (const float*)d_in[3]; // [2,128,512]
    const float* W    = (const float*)d_in[4]; // [64,96]
    const float* bias = (const float*)d_in[5]; // [64]
    float* y = (float*)d_out;                  // [2,256,64,128]

    float* ws = (float*)d_ws;
    float* wT = ws;                  // 131072 floats  [b,n,t]
    float* s  = ws + 131072;         // 131072 floats  [bi,m,t]
    float* u  = ws + 262144;         // 4194304 floats [bi,m,d,t]
    // total ws use: 4456448 floats = 17.8 MB

    k_wt <<<dim3(16, 4, 2), 256, 0, stream>>>(mask, wT);
    k_s  <<<dim3(256, 4), 128, 0, stream>>>(adj, wT, s);
    k_u  <<<dim3(8, 32, 4), 256, 0, stream>>>(fc, adj, wT, u);
    k_mlp<<<dim3(256, 2), 256, 0, stream>>>(ft, u, s, W, bias, y);
}

// Round 3
// 147.652 us; speedup vs baseline: 1.2066x; 1.2066x over previous
//
#include <hip/hip_runtime.h>
#include <cstdint>
#include <cstddef>

// Shapes: b=2, n=512, m=256, d=32, t=128, ORDER=2, C_OUT=64. All I/O fp32.
// Pipeline:
//   k_adj : adj fp32 -> bf16                       [4][256][512]
//   k_g   : gt[b][j][n] = bf16(fc[b][n][j] * (1-mask[b][t][n])) for j=d*128+t<4096
//           gt[b][4096+t][n] = bf16(1-mask[b][t][n])   (extra "s" channels)
//   k_gemm: u[bi][m][j] = bf16( sum_n adjb[bi][m][n] * gt[b][j][n] )   (MFMA, j=0..4223;
//           j>=4096 gives s[bi][m][t])
//   k_mlp : y = relu(bias + W @ [ft; ft+u0*r0; ft+u1*r1]),  r_i[t] = 1/(s_i[t]+1)

using shortx8 = __attribute__((ext_vector_type(8))) short;
using floatx4 = __attribute__((ext_vector_type(4))) float;

__device__ __forceinline__ float b2f(unsigned short u) {
    union { unsigned int i; float f; } v; v.i = ((unsigned int)u) << 16; return v.f;
}
__device__ __forceinline__ unsigned short f2b(float f) {
    union { float f; unsigned int i; } v; v.f = f;
    unsigned int x = v.i;
    return (unsigned short)((x + 0x7FFFu + ((x >> 16) & 1u)) >> 16); // RNE
}

// ---------- adj fp32 -> bf16 (524288 elems) ----------
__global__ void k_adj(const float* __restrict__ adj, unsigned short* __restrict__ adjb) {
    int i4 = (blockIdx.x * 256 + threadIdx.x) * 4;
    float4 v = *(const float4*)(adj + i4);
    ushort4 o;
    o.x = f2b(v.x); o.y = f2b(v.y); o.z = f2b(v.z); o.w = f2b(v.w);
    *(ushort4*)(adjb + i4) = o;
}

// ---------- build gt[b][j][n] (transposed, bf16, with s-channels) ----------
// grid (132, 16, 2): jb (32-wide j tiles; jb>=128 -> s rows), nb (32-wide n tiles), b
__global__ void k_g(const float* __restrict__ fc, const float* __restrict__ mask,
                    unsigned short* __restrict__ gt) {
    const int jb = blockIdx.x, nb = blockIdx.y, b = blockIdx.z;
    const int tid = threadIdx.x;
    const int n0 = nb * 32;
    const int r = tid >> 3, c4 = (tid & 7) * 4;   // r: 0..31 rows, c4: 0..28 cols
    if (jb >= 128) {  // straight copy rows: gt[4096+t][n] = 1-mask[t][n]
        const int t0 = (jb - 128) * 32;
        float4 mv = *(const float4*)(mask + ((size_t)b * 128 + t0 + r) * 512 + n0 + c4);
        ushort4 o;
        o.x = f2b(1.f - mv.x); o.y = f2b(1.f - mv.y);
        o.z = f2b(1.f - mv.z); o.w = f2b(1.f - mv.w);
        *(ushort4*)(gt + ((size_t)b * 4224 + 4096 + t0 + r) * 512 + n0 + c4) = o;
        return;
    }
    const int j0 = jb * 32;
    const int t0 = j0 & 127;      // 32-aligned, within one d-channel
    __shared__ float wls[32][33];          // [t_off][n_off] = 1-mask
    __shared__ unsigned short tls[32][34]; // [j_off][n_off] transposed g
    // mask tile (coalesced over n)
    {
        float4 mv = *(const float4*)(mask + ((size_t)b * 128 + t0 + r) * 512 + n0 + c4);
        wls[r][c4 + 0] = 1.f - mv.x; wls[r][c4 + 1] = 1.f - mv.y;
        wls[r][c4 + 2] = 1.f - mv.z; wls[r][c4 + 3] = 1.f - mv.w;
    }
    // fc tile (coalesced over j); r is n_off here
    float4 fv = *(const float4*)(fc + ((size_t)b * 512 + n0 + r) * 4096 + j0 + c4);
    __syncthreads();
    tls[c4 + 0][r] = f2b(fv.x * wls[c4 + 0][r]);
    tls[c4 + 1][r] = f2b(fv.y * wls[c4 + 1][r]);
    tls[c4 + 2][r] = f2b(fv.z * wls[c4 + 2][r]);
    tls[c4 + 3][r] = f2b(fv.w * wls[c4 + 3][r]);
    __syncthreads();
    ushort4 o;
    o.x = tls[r][c4 + 0]; o.y = tls[r][c4 + 1];
    o.z = tls[r][c4 + 2]; o.w = tls[r][c4 + 3];
    *(ushort4*)(gt + ((size_t)b * 4224 + j0 + r) * 512 + n0 + c4) = o;
}

// ---------- MFMA GEMM: u[bi][m][j] = sum_n adjb[bi][m][n] * gt[b][j][n] ----------
// grid (66, 4, 4): jt (64-wide j), mt (64-wide m), bi. 256 thr = 4 waves.
// Wave w: rows m0 = mt*64+w*16 .. +15, cols j0 .. j0+63 (4 MFMA tiles). No LDS.
__launch_bounds__(256)
__global__ void k_gemm(const unsigned short* __restrict__ adjb,
                       const unsigned short* __restrict__ gt,
                       unsigned short* __restrict__ u) {
    const int jt = blockIdx.x, mt = blockIdx.y, bi = blockIdx.z;
    const int b = bi >> 1;
    const int tid = threadIdx.x;
    const int wave = tid >> 6, lane = tid & 63;
    const int l15 = lane & 15, quad = lane >> 4;
    const int m0 = mt * 64 + wave * 16;
    const int j0 = jt * 64;

    const unsigned short* Ap = adjb + ((size_t)(bi * 256 + m0 + l15)) * 512 + quad * 8;
    const unsigned short* Bp = gt + ((size_t)b * 4224 + j0 + l15) * 512 + quad * 8;

    floatx4 acc0 = {0.f, 0.f, 0.f, 0.f};
    floatx4 acc1 = {0.f, 0.f, 0.f, 0.f};
    floatx4 acc2 = {0.f, 0.f, 0.f, 0.f};
    floatx4 acc3 = {0.f, 0.f, 0.f, 0.f};

    #pragma unroll 4
    for (int k0 = 0; k0 < 512; k0 += 32) {
        shortx8 a  = *(const shortx8*)(Ap + k0);
        shortx8 b0 = *(const shortx8*)(Bp + k0);
        shortx8 b1 = *(const shortx8*)(Bp + 16 * 512 + k0);
        shortx8 b2 = *(const shortx8*)(Bp + 32 * 512 + k0);
        shortx8 b3 = *(const shortx8*)(Bp + 48 * 512 + k0);
        acc0 = __builtin_amdgcn_mfma_f32_16x16x32_bf16(a, b0, acc0, 0, 0, 0);
        acc1 = __builtin_amdgcn_mfma_f32_16x16x32_bf16(a, b1, acc1, 0, 0, 0);
        acc2 = __builtin_amdgcn_mfma_f32_16x16x32_bf16(a, b2, acc2, 0, 0, 0);
        acc3 = __builtin_amdgcn_mfma_f32_16x16x32_bf16(a, b3, acc3, 0, 0, 0);
    }
    // C/D: col = lane&15 (j), row = quad*4+reg (m)
    unsigned short* up = u + ((size_t)(bi * 256 + m0 + quad * 4)) * 4224 + j0 + l15;
    #pragma unroll
    for (int reg = 0; reg < 4; ++reg) {
        up[(size_t)reg * 4224 + 0]  = f2b(acc0[reg]);
        up[(size_t)reg * 4224 + 16] = f2b(acc1[reg]);
        up[(size_t)reg * 4224 + 32] = f2b(acc2[reg]);
        up[(size_t)reg * 4224 + 48] = f2b(acc3[reg]);
    }
}

// ---------- fused MLP: y[b,m,o,t] = relu(bias + W@[ft; ft+u0*r0; ft+u1*r1]) ----------
// grid (256, 2): m, b. 256 threads. X staged in LDS once (no redundant global reads).
__launch_bounds__(256)
__global__ void k_mlp(const float* __restrict__ ft, const unsigned short* __restrict__ u,
                      const float* __restrict__ W, const float* __restrict__ bias,
                      float* __restrict__ y) {
    const int m = blockIdx.x, b = blockIdx.y;
    const int tid = threadIdx.x;
    __shared__ float Xl[96 * 128];
    __shared__ float Wl[64 * 97];
    __shared__ float bl[64];
    __shared__ float r0l[128], r1l[128];

    const unsigned short* up0 = u + ((size_t)(b * 2 + 0) * 256 + m) * 4224;
    const unsigned short* up1 = u + ((size_t)(b * 2 + 1) * 256 + m) * 4224;

    if (tid < 128)       r0l[tid]       = 1.f / (b2f(up0[4096 + tid]) + 1.f);
    else                 r1l[tid - 128] = 1.f / (b2f(up1[4096 + tid - 128]) + 1.f);
    for (int idx = tid; idx < 6144; idx += 256) {
        int o = idx / 96, c = idx - o * 96;
        Wl[o * 97 + c] = W[idx];
    }
    if (tid < 64) bl[tid] = bias[tid];
    __syncthreads();

    // X fill: thread handles 16 consecutive j within one d-row c
    {
        const int c  = tid >> 3;
        const int tv = (tid & 7) * 16;
        const float* fp = ft + ((size_t)b * 256 + m) * 4096 + (size_t)c * 128 + tv;
        const unsigned short* q0 = up0 + (size_t)c * 128 + tv;
        const unsigned short* q1 = up1 + (size_t)c * 128 + tv;
        float fv[16];
        *(float4*)(fv + 0)  = *(const float4*)(fp + 0);
        *(float4*)(fv + 4)  = *(const float4*)(fp + 4);
        *(float4*)(fv + 8)  = *(const float4*)(fp + 8);
        *(float4*)(fv + 12) = *(const float4*)(fp + 12);
        uint4 raw0a = *(const uint4*)(q0);      // 8 bf16
        uint4 raw0b = *(const uint4*)(q0 + 8);
        uint4 raw1a = *(const uint4*)(q1);
        uint4 raw1b = *(const uint4*)(q1 + 8);
        const unsigned short* pu0a = (const unsigned short*)&raw0a;
        const unsigned short* pu0b = (const unsigned short*)&raw0b;
        const unsigned short* pu1a = (const unsigned short*)&raw1a;
        const unsigned short* pu1b = (const unsigned short*)&raw1b;
        float* X1 = &Xl[(size_t)c * 128 + tv];
        float* X2 = &Xl[(size_t)(32 + c) * 128 + tv];
        float* X3 = &Xl[(size_t)(64 + c) * 128 + tv];
        #pragma unroll
        for (int i = 0; i < 16; ++i) {
            float f = fv[i];
            float u0v = b2f(i < 8 ? pu0a[i] : pu0b[i - 8]);
            float u1v = b2f(i < 8 ? pu1a[i] : pu1b[i - 8]);
            X1[i] = f;
            X2[i] = f + u0v * r0l[tv + i];
            X3[i] = f + u1v * r1l[tv + i];
        }
    }
    __syncthreads();

    const int og = tid >> 4, tg = tid & 15, t0 = tg * 8;
    float acc[4][8];
    #pragma unroll
    for (int i = 0; i < 4; ++i) {
        float bv = bl[og * 4 + i];
        #pragma unroll
        for (int k = 0; k < 8; ++k) acc[i][k] = bv;
    }
    for (int c = 0; c < 96; ++c) {
        float x[8];
        *(float4*)(x + 0) = *(const float4*)&Xl[(size_t)c * 128 + t0];
        *(float4*)(x + 4) = *(const float4*)&Xl[(size_t)c * 128 + t0 + 4];
        float w0 = Wl[(og * 4 + 0) * 97 + c];
        float w1 = Wl[(og * 4 + 1) * 97 + c];
        float w2 = Wl[(og * 4 + 2) * 97 + c];
        float w3 = Wl[(og * 4 + 3) * 97 + c];
        #pragma unroll
        for (int k = 0; k < 8; ++k) {
            acc[0][k] += w0 * x[k];
            acc[1][k] += w1 * x[k];
            acc[2][k] += w2 * x[k];
            acc[3][k] += w3 * x[k];
        }
    }
    float* yp = y + (((size_t)b * 256 + m) * 64 + og * 4) * 128 + t0;
    #pragma unroll
    for (int i = 0; i < 4; ++i) {
        float4 pa, pb;
        pa.x = acc[i][0] > 0.f ? acc[i][0] : 0.f;
        pa.y = acc[i][1] > 0.f ? acc[i][1] : 0.f;
        pa.z = acc[i][2] > 0.f ? acc[i][2] : 0.f;
        pa.w = acc[i][3] > 0.f ? acc[i][3] : 0.f;
        pb.x = acc[i][4] > 0.f ? acc[i][4] : 0.f;
        pb.y = acc[i][5] > 0.f ? acc[i][5] : 0.f;
        pb.z = acc[i][6] > 0.f ? acc[i][6] : 0.f;
        pb.w = acc[i][7] > 0.f ? acc[i][7] : 0.f;
        *(float4*)(yp + (size_t)i * 128 + 0) = pa;
        *(float4*)(yp + (size_t)i * 128 + 4) = pb;
    }
}

extern "C" void kernel_launch(void* const* d_in, const int* in_sizes, int n_in,
                              void* d_out, int out_size, void* d_ws, size_t ws_size,
                              hipStream_t stream) {
    const float* fc   = (const float*)d_in[0]; // [2,512,32,128]
    const float* ft   = (const float*)d_in[1]; // [2,256,32,128]
    const float* adj  = (const float*)d_in[2]; // [2,2,256,512]
    const float* mask = (const float*)d_in[3]; // [2,128,512]
    const float* W    = (const float*)d_in[4]; // [64,96]
    const float* bias = (const float*)d_in[5]; // [64]
    float* y = (float*)d_out;                  // [2,256,64,128]

    unsigned short* gt   = (unsigned short*)d_ws;      // [2][4224][512] bf16
    unsigned short* adjb = gt + (size_t)2 * 4224 * 512;   // [4][256][512] bf16
    unsigned short* u    = adjb + (size_t)4 * 256 * 512;  // [4][256][4224] bf16
    // total ws: 18,350,080 bytes

    k_adj <<<512, 256, 0, stream>>>(adj, adjb);
    k_g   <<<dim3(132, 16, 2), 256, 0, stream>>>(fc, mask, gt);
    k_gemm<<<dim3(66, 4, 4), 256, 0, stream>>>(adjb, gt, u);
    k_mlp <<<dim3(256, 2), 256, 0, stream>>>(ft, u, W, bias, y);
}

// Round 4
// 115.171 us; speedup vs baseline: 1.5469x; 1.2820x over previous
//
#include <hip/hip_runtime.h>
#include <cstdint>
#include <cstddef>

// Shapes: b=2, n=512, m=256, d=32, t=128, ORDER=2, C_OUT=64. All I/O fp32.
// Pipeline:
//   k_adj : adj fp32 -> bf16                       [4][256][512]
//   k_g   : gt[b][j][n] = bf16(fc[b][n][j] * (1-mask[b][t][n])) for j=d*128+t<4096
//           gt[b][4096+t][n] = bf16(1-mask[b][t][n])   (extra "s" channels)
//   k_gemm: u[bi][m][j] = bf16( sum_n adjb[bi][m][n] * gt[b][j][n] )   MFMA,
//           m97-style LDS staging via global_load_lds (async), 128x128 tile, BK=32
//   k_mlp : y = relu(bias + W @ [ft; ft+u0*r0; ft+u1*r1]),  r_i[t] = 1/(s_i[t]+1)

using shortx8 = __attribute__((ext_vector_type(8))) short;
using floatx4 = __attribute__((ext_vector_type(4))) float;

__device__ __forceinline__ float b2f(unsigned short u) {
    union { unsigned int i; float f; } v; v.i = ((unsigned int)u) << 16; return v.f;
}
__device__ __forceinline__ unsigned short f2b(float f) {
    union { float f; unsigned int i; } v; v.f = f;
    unsigned int x = v.i;
    return (unsigned short)((x + 0x7FFFu + ((x >> 16) & 1u)) >> 16); // RNE
}
// async global->LDS, 16B per lane; lds dest = wave-uniform base + lane*16
__device__ __forceinline__ void gl_lds16(const unsigned short* g, unsigned short* l) {
    __builtin_amdgcn_global_load_lds(
        (const __attribute__((address_space(1))) unsigned int*)g,
        (__attribute__((address_space(3))) unsigned int*)l, 16, 0, 0);
}

// ---------- adj fp32 -> bf16 (524288 elems) ----------
__global__ void k_adj(const float* __restrict__ adj, unsigned short* __restrict__ adjb) {
    int i4 = (blockIdx.x * 256 + threadIdx.x) * 4;
    float4 v = *(const float4*)(adj + i4);
    ushort4 o;
    o.x = f2b(v.x); o.y = f2b(v.y); o.z = f2b(v.z); o.w = f2b(v.w);
    *(ushort4*)(adjb + i4) = o;
}

// ---------- build gt[b][j][n] (transposed, bf16, with s-channels) ----------
__global__ void k_g(const float* __restrict__ fc, const float* __restrict__ mask,
                    unsigned short* __restrict__ gt) {
    const int jb = blockIdx.x, nb = blockIdx.y, b = blockIdx.z;
    const int tid = threadIdx.x;
    const int n0 = nb * 32;
    const int r = tid >> 3, c4 = (tid & 7) * 4;
    if (jb >= 128) {  // gt[4096+t][n] = 1-mask[t][n]
        const int t0 = (jb - 128) * 32;
        float4 mv = *(const float4*)(mask + ((size_t)b * 128 + t0 + r) * 512 + n0 + c4);
        ushort4 o;
        o.x = f2b(1.f - mv.x); o.y = f2b(1.f - mv.y);
        o.z = f2b(1.f - mv.z); o.w = f2b(1.f - mv.w);
        *(ushort4*)(gt + ((size_t)b * 4224 + 4096 + t0 + r) * 512 + n0 + c4) = o;
        return;
    }
    const int j0 = jb * 32;
    const int t0 = j0 & 127;
    __shared__ float wls[32][33];
    __shared__ unsigned short tls[32][34];
    {
        float4 mv = *(const float4*)(mask + ((size_t)b * 128 + t0 + r) * 512 + n0 + c4);
        wls[r][c4 + 0] = 1.f - mv.x; wls[r][c4 + 1] = 1.f - mv.y;
        wls[r][c4 + 2] = 1.f - mv.z; wls[r][c4 + 3] = 1.f - mv.w;
    }
    float4 fv = *(const float4*)(fc + ((size_t)b * 512 + n0 + r) * 4096 + j0 + c4);
    __syncthreads();
    tls[c4 + 0][r] = f2b(fv.x * wls[c4 + 0][r]);
    tls[c4 + 1][r] = f2b(fv.y * wls[c4 + 1][r]);
    tls[c4 + 2][r] = f2b(fv.z * wls[c4 + 2][r]);
    tls[c4 + 3][r] = f2b(fv.w * wls[c4 + 3][r]);
    __syncthreads();
    ushort4 o;
    o.x = tls[r][c4 + 0]; o.y = tls[r][c4 + 1];
    o.z = tls[r][c4 + 2]; o.w = tls[r][c4 + 3];
    *(ushort4*)(gt + ((size_t)b * 4224 + j0 + r) * 512 + n0 + c4) = o;
}

// ---------- MFMA GEMM (m97-style): u[bi][m][j] = sum_n adjb[bi][m][n]*gt[b][j][n] ----------
// grid (33, 2, 4): jt (128-wide j), mt (128-wide m), bi. 256 thr = 4 waves (2x2).
// Wave (wm,wj) computes 64x64 via 4x4 MFMA 16x16x32. LDS staged async, BK=32.
__launch_bounds__(256, 1)
__global__ void k_gemm(const unsigned short* __restrict__ adjb,
                       const unsigned short* __restrict__ gt,
                       unsigned short* __restrict__ u) {
    const int jt = blockIdx.x, mt = blockIdx.y, bi = blockIdx.z;
    const int b = bi >> 1;
    const int tid = threadIdx.x;
    const int wave = tid >> 6, lane = tid & 63;
    const int l15 = lane & 15, quad = lane >> 4;
    const int wm = wave >> 1, wj = wave & 1;

    __shared__ __align__(16) unsigned short Al[128 * 32];  // [m][k] 8KB
    __shared__ __align__(16) unsigned short Bl[128 * 32];  // [j][k] 8KB

    // staging: chunk = 64 lanes * 16B = 512 shorts = 16 rows; lane covers
    // row chunk*16 + (lane>>2), k-slot (lane&3)*8.
    const int srow = lane >> 2;
    const int skq  = (lane & 3) * 8;
    const unsigned short* Ag = adjb + ((size_t)bi * 256 + mt * 128) * 512;
    const unsigned short* Bg = gt   + ((size_t)b * 4224 + jt * 128) * 512;

    floatx4 acc[4][4];
    #pragma unroll
    for (int i = 0; i < 4; ++i)
        #pragma unroll
        for (int j = 0; j < 4; ++j) acc[i][j] = (floatx4){0.f, 0.f, 0.f, 0.f};

    for (int k0 = 0; k0 < 512; k0 += 32) {
        __syncthreads();   // previous tile fully consumed before overwrite
        #pragma unroll
        for (int r = 0; r < 2; ++r) {
            const int ch = wave * 2 + r;                  // 0..7
            const int row = ch * 16 + srow;
            gl_lds16(Ag + (size_t)row * 512 + k0 + skq, &Al[ch * 512]);
            gl_lds16(Bg + (size_t)row * 512 + k0 + skq, &Bl[ch * 512]);
        }
        __syncthreads();   // drains vmcnt (compiler) + barrier

        shortx8 af[4], bf[4];
        #pragma unroll
        for (int i = 0; i < 4; ++i)
            af[i] = *(const shortx8*)&Al[(wm * 64 + i * 16 + l15) * 32 + quad * 8];
        #pragma unroll
        for (int j = 0; j < 4; ++j)
            bf[j] = *(const shortx8*)&Bl[(wj * 64 + j * 16 + l15) * 32 + quad * 8];
        #pragma unroll
        for (int i = 0; i < 4; ++i)
            #pragma unroll
            for (int j = 0; j < 4; ++j)
                acc[i][j] = __builtin_amdgcn_mfma_f32_16x16x32_bf16(af[i], bf[j], acc[i][j], 0, 0, 0);
    }

    // C/D: col = l15 (j), row = quad*4+reg (m)
    unsigned short* up = u + ((size_t)(bi * 256 + mt * 128 + wm * 64 + quad * 4)) * 4224
                           + jt * 128 + wj * 64 + l15;
    #pragma unroll
    for (int i = 0; i < 4; ++i)
        #pragma unroll
        for (int j = 0; j < 4; ++j)
            #pragma unroll
            for (int reg = 0; reg < 4; ++reg)
                up[(size_t)(i * 16 + reg) * 4224 + j * 16] = f2b(acc[i][j][reg]);
}

// ---------- fused MLP: y[b,m,o,t] = relu(bias + W@[ft; ft+u0*r0; ft+u1*r1]) ----------
__launch_bounds__(256)
__global__ void k_mlp(const float* __restrict__ ft, const unsigned short* __restrict__ u,
                      const float* __restrict__ W, const float* __restrict__ bias,
                      float* __restrict__ y) {
    const int m = blockIdx.x, b = blockIdx.y;
    const int tid = threadIdx.x;
    __shared__ float Xl[96 * 128];
    __shared__ float Wl[64 * 97];
    __shared__ float bl[64];
    __shared__ float r0l[128], r1l[128];

    const unsigned short* up0 = u + ((size_t)(b * 2 + 0) * 256 + m) * 4224;
    const unsigned short* up1 = u + ((size_t)(b * 2 + 1) * 256 + m) * 4224;

    if (tid < 128)       r0l[tid]       = 1.f / (b2f(up0[4096 + tid]) + 1.f);
    else                 r1l[tid - 128] = 1.f / (b2f(up1[4096 + tid - 128]) + 1.f);
    for (int idx = tid; idx < 6144; idx += 256) {
        int o = idx / 96, c = idx - o * 96;
        Wl[o * 97 + c] = W[idx];
    }
    if (tid < 64) bl[tid] = bias[tid];
    __syncthreads();

    {
        const int c  = tid >> 3;
        const int tv = (tid & 7) * 16;
        const float* fp = ft + ((size_t)b * 256 + m) * 4096 + (size_t)c * 128 + tv;
        const unsigned short* q0 = up0 + (size_t)c * 128 + tv;
        const unsigned short* q1 = up1 + (size_t)c * 128 + tv;
        float fv[16];
        *(float4*)(fv + 0)  = *(const float4*)(fp + 0);
        *(float4*)(fv + 4)  = *(const float4*)(fp + 4);
        *(float4*)(fv + 8)  = *(const float4*)(fp + 8);
        *(float4*)(fv + 12) = *(const float4*)(fp + 12);
        uint4 raw0a = *(const uint4*)(q0);
        uint4 raw0b = *(const uint4*)(q0 + 8);
        uint4 raw1a = *(const uint4*)(q1);
        uint4 raw1b = *(const uint4*)(q1 + 8);
        const unsigned short* pu0a = (const unsigned short*)&raw0a;
        const unsigned short* pu0b = (const unsigned short*)&raw0b;
        const unsigned short* pu1a = (const unsigned short*)&raw1a;
        const unsigned short* pu1b = (const unsigned short*)&raw1b;
        float* X1 = &Xl[(size_t)c * 128 + tv];
        float* X2 = &Xl[(size_t)(32 + c) * 128 + tv];
        float* X3 = &Xl[(size_t)(64 + c) * 128 + tv];
        #pragma unroll
        for (int i = 0; i < 16; ++i) {
            float f = fv[i];
            float u0v = b2f(i < 8 ? pu0a[i] : pu0b[i - 8]);
            float u1v = b2f(i < 8 ? pu1a[i] : pu1b[i - 8]);
            X1[i] = f;
            X2[i] = f + u0v * r0l[tv + i];
            X3[i] = f + u1v * r1l[tv + i];
        }
    }
    __syncthreads();

    const int og = tid >> 4, tg = tid & 15, t0 = tg * 8;
    float acc[4][8];
    #pragma unroll
    for (int i = 0; i < 4; ++i) {
        float bv = bl[og * 4 + i];
        #pragma unroll
        for (int k = 0; k < 8; ++k) acc[i][k] = bv;
    }
    for (int c = 0; c < 96; ++c) {
        float x[8];
        *(float4*)(x + 0) = *(const float4*)&Xl[(size_t)c * 128 + t0];
        *(float4*)(x + 4) = *(const float4*)&Xl[(size_t)c * 128 + t0 + 4];
        float w0 = Wl[(og * 4 + 0) * 97 + c];
        float w1 = Wl[(og * 4 + 1) * 97 + c];
        float w2 = Wl[(og * 4 + 2) * 97 + c];
        float w3 = Wl[(og * 4 + 3) * 97 + c];
        #pragma unroll
        for (int k = 0; k < 8; ++k) {
            acc[0][k] += w0 * x[k];
            acc[1][k] += w1 * x[k];
            acc[2][k] += w2 * x[k];
            acc[3][k] += w3 * x[k];
        }
    }
    float* yp = y + (((size_t)b * 256 + m) * 64 + og * 4) * 128 + t0;
    #pragma unroll
    for (int i = 0; i < 4; ++i) {
        float4 pa, pb;
        pa.x = acc[i][0] > 0.f ? acc[i][0] : 0.f;
        pa.y = acc[i][1] > 0.f ? acc[i][1] : 0.f;
        pa.z = acc[i][2] > 0.f ? acc[i][2] : 0.f;
        pa.w = acc[i][3] > 0.f ? acc[i][3] : 0.f;
        pb.x = acc[i][4] > 0.f ? acc[i][4] : 0.f;
        pb.y = acc[i][5] > 0.f ? acc[i][5] : 0.f;
        pb.z = acc[i][6] > 0.f ? acc[i][6] : 0.f;
        pb.w = acc[i][7] > 0.f ? acc[i][7] : 0.f;
        *(float4*)(yp + (size_t)i * 128 + 0) = pa;
        *(float4*)(yp + (size_t)i * 128 + 4) = pb;
    }
}

extern "C" void kernel_launch(void* const* d_in, const int* in_sizes, int n_in,
                              void* d_out, int out_size, void* d_ws, size_t ws_size,
                              hipStream_t stream) {
    const float* fc   = (const float*)d_in[0]; // [2,512,32,128]
    const float* ft   = (const float*)d_in[1]; // [2,256,32,128]
    const float* adj  = (const float*)d_in[2]; // [2,2,256,512]
    const float* mask = (const float*)d_in[3]; // [2,128,512]
    const float* W    = (const float*)d_in[4]; // [64,96]
    const float* bias = (const float*)d_in[5]; // [64]
    float* y = (float*)d_out;                  // [2,256,64,128]

    unsigned short* gt   = (unsigned short*)d_ws;         // [2][4224][512] bf16
    unsigned short* adjb = gt + (size_t)2 * 4224 * 512;   // [4][256][512] bf16
    unsigned short* u    = adjb + (size_t)4 * 256 * 512;  // [4][256][4224] bf16

    k_adj <<<512, 256, 0, stream>>>(adj, adjb);
    k_g   <<<dim3(132, 16, 2), 256, 0, stream>>>(fc, mask, gt);
    k_gemm<<<dim3(33, 2, 4), 256, 0, stream>>>(adjb, gt, u);
    k_mlp <<<dim3(256, 2), 256, 0, stream>>>(ft, u, W, bias, y);
}